// Round 13
// baseline (291.235 us; speedup 1.0000x reference)
//
#include <hip/hip_runtime.h>
#include <hip/hip_bf16.h>

#define NPIX 65536
#define IW 256

typedef unsigned short ushort_t;
typedef __attribute__((ext_vector_type(8))) short bf16x8;
typedef __attribute__((ext_vector_type(4))) float f32x4;

__device__ __forceinline__ float b2f(ushort_t u) {
    union { unsigned int i; float f; } v;
    v.i = ((unsigned int)u) << 16;
    return v.f;
}
__device__ __forceinline__ ushort_t f2b(float f) {
    __hip_bfloat16 h = __float2bfloat16(f);
    return *reinterpret_cast<ushort_t*>(&h);
}

// ---------------- KGEMM (B-stationary 64n tile, fused transpose, A-reg prefetch)
// C[m][n] = sum_k A[m][k] * B[k][n];  B source row-major [192][NPIX].
// grid (1024 n-tiles, nb batches). LDS 51.2 KB -> 3 blocks/CU (12 waves).
template<int B_F32, int A_BF16, int OUT_BF16>
__global__ __launch_bounds__(256) void kgemm_fused(const void* __restrict__ Aptr,
                                                   const void* __restrict__ Bsrc,
                                                   void* __restrict__ Cout,
                                                   int mtiles, long Astr, long Bstr, long Cstr) {
    __shared__ ushort_t Bs[64 * 200];     // 25.6 KB
    __shared__ ushort_t AsLu[64 * 200];   // Lu[192][66] during B-stage; As after
    const int tid = threadIdx.x;
    const int lane = tid & 63;
    const int wave = tid >> 6;
    const int batch = blockIdx.y;
    const long n_base = (long)blockIdx.x * 64;

    // ---- prefetch A tile 0 into registers (bf16-packed)
    ushort4 areg[12];
    #pragma unroll
    for (int i = 0; i < 12; i++) {
        int c = tid + i * 256;
        int m = c / 48, k4 = c % 48;
        if (A_BF16) {
            const ushort_t* A = (const ushort_t*)Aptr + batch * Astr;
            areg[i] = *reinterpret_cast<const ushort4*>(A + (long)m * 192 + k4 * 4);
        } else {
            const float* A = (const float*)Aptr + batch * Astr;
            float4 v = *reinterpret_cast<const float4*>(A + (long)m * 192 + k4 * 4);
            areg[i] = make_ushort4(f2b(v.x), f2b(v.y), f2b(v.z), f2b(v.w));
        }
    }

    // ---- B-stage with in-LDS transpose: single 64-px pass
    ushort_t (*Lu)[66] = reinterpret_cast<ushort_t (*)[66]>(AsLu);
    #pragma unroll
    for (int i = 0; i < 24; i++) {         // 192 rows x 32 elem-pairs
        int e = tid + i * 256;
        int k = e >> 5, n2 = e & 31;
        ushort2 o;
        if (B_F32) {
            float2 v = *reinterpret_cast<const float2*>(
                (const float*)Bsrc + batch * Bstr + (long)k * NPIX + n_base + n2 * 2);
            o = make_ushort2(f2b(v.x), f2b(v.y));
        } else {
            o = *reinterpret_cast<const ushort2*>(
                (const ushort_t*)Bsrc + batch * Bstr + (long)k * NPIX + n_base + n2 * 2);
        }
        *reinterpret_cast<ushort2*>(&Lu[k][n2 * 2]) = o;
    }
    __syncthreads();
    {
        const int n = tid >> 2, seg = tid & 3;
        const int kb = seg * 48;
        ushort_t* dst = &Bs[n * 200 + kb];
        #pragma unroll
        for (int w = 0; w < 6; w++) {
            unsigned int p0 = (unsigned int)Lu[kb + w * 8 + 0][n] | ((unsigned int)Lu[kb + w * 8 + 1][n] << 16);
            unsigned int p1 = (unsigned int)Lu[kb + w * 8 + 2][n] | ((unsigned int)Lu[kb + w * 8 + 3][n] << 16);
            unsigned int p2 = (unsigned int)Lu[kb + w * 8 + 4][n] | ((unsigned int)Lu[kb + w * 8 + 5][n] << 16);
            unsigned int p3 = (unsigned int)Lu[kb + w * 8 + 6][n] | ((unsigned int)Lu[kb + w * 8 + 7][n] << 16);
            *reinterpret_cast<int4*>(dst + w * 8) = make_int4(p0, p1, p2, p3);
        }
        if (seg == 3)
            *reinterpret_cast<int4*>(&Bs[n * 200 + 192]) = make_int4(0, 0, 0, 0);
    }

    const int r15 = lane & 15;
    const int g8 = (lane >> 4) * 8;
    const int gq = (lane >> 4) * 4;
    const int nw = wave * 16;

    // ---- m-tile loop; AsLu holds the A tile, next tile prefetched in regs
    for (int mt = 0; mt < mtiles; mt++) {
        __syncthreads();   // Lu pack reads done (mt=0) / prev MFMA reads done
        #pragma unroll
        for (int i = 0; i < 12; i++) {
            int c = tid + i * 256;
            int m = c / 48, k4 = c % 48;
            *reinterpret_cast<ushort4*>(&AsLu[m * 200 + k4 * 4]) = areg[i];
        }
        if (mt + 1 < mtiles) {   // prefetch next A tile; latency hides under MFMA
            #pragma unroll
            for (int i = 0; i < 12; i++) {
                int c = tid + i * 256;
                int m = (mt + 1) * 64 + c / 48, k4 = c % 48;
                if (A_BF16) {
                    const ushort_t* A = (const ushort_t*)Aptr + batch * Astr;
                    areg[i] = *reinterpret_cast<const ushort4*>(A + (long)m * 192 + k4 * 4);
                } else {
                    const float* A = (const float*)Aptr + batch * Astr;
                    float4 v = *reinterpret_cast<const float4*>(A + (long)m * 192 + k4 * 4);
                    areg[i] = make_ushort4(f2b(v.x), f2b(v.y), f2b(v.z), f2b(v.w));
                }
            }
        }
        __syncthreads();

        f32x4 acc[4];
        #pragma unroll
        for (int mi = 0; mi < 4; mi++) acc[mi] = (f32x4){0.f, 0.f, 0.f, 0.f};

        #pragma unroll
        for (int kk = 0; kk < 192; kk += 32) {
            bf16x8 b = *reinterpret_cast<const bf16x8*>(&Bs[(nw + r15) * 200 + kk + g8]);
            bf16x8 a[4];
            #pragma unroll
            for (int mi = 0; mi < 4; mi++)
                a[mi] = *reinterpret_cast<const bf16x8*>(&AsLu[(mi * 16 + r15) * 200 + kk + g8]);
            #pragma unroll
            for (int mi = 0; mi < 4; mi++)
                acc[mi] = __builtin_amdgcn_mfma_f32_16x16x32_bf16(a[mi], b, acc[mi], 0, 0, 0);
        }

        const int m_base = mt * 64;
        #pragma unroll
        for (int mi = 0; mi < 4; mi++)
            #pragma unroll
            for (int r = 0; r < 4; r++) {
                long m = m_base + mi * 16 + gq + r;
                long n = n_base + nw + r15;
                if (OUT_BF16) ((ushort_t*)Cout)[batch * Cstr + m * NPIX + n] = f2b(acc[mi][r]);
                else          ((float*)Cout)[batch * Cstr + m * NPIX + n] = acc[mi][r];
            }
    }
}

// ---------------- KDW: register-sliding-window depthwise 3x3, 16 rows/block.
__global__ __launch_bounds__(256) void kdw_conv(const ushort_t* __restrict__ qkvb,
                                                const float* __restrict__ wdw,
                                                ushort_t* __restrict__ dwb,
                                                ushort_t* __restrict__ dwv,
                                                long qstr, long dbstr, long dvstr) {
    __shared__ ushort_t rows[18][IW];
    const int tid = threadIdx.x;
    const int j = blockIdx.y;
    const int batch = blockIdx.z;
    const int y0 = blockIdx.x * 16;
    const ushort_t* src = qkvb + batch * qstr + (long)j * NPIX;
    ushort_t* dst = (j < 384) ? (dwb + batch * dbstr + (long)j * NPIX)
                              : (dwv + batch * dvstr + (long)(j - 384) * NPIX);
    float wv[9];
    #pragma unroll
    for (int t = 0; t < 9; t++) wv[t] = wdw[j * 9 + t];

    for (int e = tid; e < 18 * 64; e += 256) {
        int r = e >> 6, x4 = e & 63;
        int yy = y0 - 1 + r;
        ushort4 val = (yy >= 0 && yy <= 255)
            ? *reinterpret_cast<const ushort4*>(src + yy * IW + x4 * 4)
            : make_ushort4(0, 0, 0, 0);
        *reinterpret_cast<ushort4*>(&rows[r][x4 * 4]) = val;
    }
    __syncthreads();

    const int ty = tid >> 4;
    const int tx = (tid & 15) * 16;
    float win[3][18];
    #pragma unroll
    for (int dy = 0; dy < 3; dy++) {
        const ushort_t* rw = rows[ty + dy];
        win[dy][0] = (tx > 0) ? b2f(rw[tx - 1]) : 0.f;
        #pragma unroll
        for (int i = 0; i < 16; i++) win[dy][i + 1] = b2f(rw[tx + i]);
        win[dy][17] = (tx < 240) ? b2f(rw[tx + 16]) : 0.f;
    }

    unsigned int packed[8];
    #pragma unroll
    for (int p2 = 0; p2 < 8; p2++) {
        unsigned int pk = 0;
        #pragma unroll
        for (int half = 0; half < 2; half++) {
            const int p = p2 * 2 + half;
            float a = 0.f;
            #pragma unroll
            for (int dy = 0; dy < 3; dy++)
                #pragma unroll
                for (int dx = 0; dx < 3; dx++)
                    a += wv[dy * 3 + dx] * win[dy][p + dx];
            pk |= ((unsigned int)f2b(a)) << (16 * half);
        }
        packed[p2] = pk;
    }
    int4* dp = reinterpret_cast<int4*>(dst + (y0 + ty) * IW + tx);
    dp[0] = make_int4(packed[0], packed[1], packed[2], packed[3]);
    dp[1] = make_int4(packed[4], packed[5], packed[6], packed[7]);
}

// ---------------- K2G: MFMA Gram partials, fragments straight from global.
__global__ __launch_bounds__(256) void k2_gram_mfma(const ushort_t* __restrict__ dwb,
                                                    float* __restrict__ Spt,
                                                    float* __restrict__ sqp,
                                                    long dbstr, long Sptstr, long sqpstr) {
    const int tid = threadIdx.x;
    const int lane = tid & 63;
    const int wave = tid >> 6;
    const int chunk = blockIdx.x;
    const int h = blockIdx.y;
    const int batch = blockIdx.z;
    const int r15 = lane & 15;
    const int g = lane >> 4;
    const long n0 = (long)chunk * 1024 + wave * 256;
    const ushort_t* qb = dwb + batch * dbstr + (long)(h * 48) * NPIX + n0;
    const ushort_t* kb = dwb + batch * dbstr + (long)(192 + h * 48) * NPIX + n0;

    f32x4 acc[3][3];
    #pragma unroll
    for (int mi = 0; mi < 3; mi++)
        #pragma unroll
        for (int nj = 0; nj < 3; nj++)
            acc[mi][nj] = (f32x4){0.f, 0.f, 0.f, 0.f};
    float ssq[3] = {0.f, 0.f, 0.f}, ssk[3] = {0.f, 0.f, 0.f};

    for (int ks = 0; ks < 8; ks++) {
        const int off = ks * 32 + g * 8;
        bf16x8 a[3], bfr[3];
        #pragma unroll
        for (int mi = 0; mi < 3; mi++)
            a[mi] = *reinterpret_cast<const bf16x8*>(qb + (long)(mi * 16 + r15) * NPIX + off);
        #pragma unroll
        for (int nj = 0; nj < 3; nj++)
            bfr[nj] = *reinterpret_cast<const bf16x8*>(kb + (long)(nj * 16 + r15) * NPIX + off);
        #pragma unroll
        for (int mi = 0; mi < 3; mi++)
            #pragma unroll
            for (int j = 0; j < 8; j++) {
                float f = b2f((ushort_t)a[mi][j]);
                ssq[mi] += f * f;
            }
        #pragma unroll
        for (int nj = 0; nj < 3; nj++)
            #pragma unroll
            for (int j = 0; j < 8; j++) {
                float f = b2f((ushort_t)bfr[nj][j]);
                ssk[nj] += f * f;
            }
        #pragma unroll
        for (int mi = 0; mi < 3; mi++)
            #pragma unroll
            for (int nj = 0; nj < 3; nj++)
                acc[mi][nj] = __builtin_amdgcn_mfma_f32_16x16x32_bf16(a[mi], bfr[nj], acc[mi][nj], 0, 0, 0);
    }

    const int cw = chunk * 4 + wave;
    float* outb = Spt + batch * Sptstr + (long)cw * 9216 + h * 2304;
    const int gq = g * 4;
    #pragma unroll
    for (int mi = 0; mi < 3; mi++)
        #pragma unroll
        for (int nj = 0; nj < 3; nj++)
            #pragma unroll
            for (int r = 0; r < 4; r++)
                outb[(mi * 16 + gq + r) * 48 + nj * 16 + r15] = acc[mi][nj][r];

    #pragma unroll
    for (int mi = 0; mi < 3; mi++) {
        ssq[mi] += __shfl_xor(ssq[mi], 16, 64);
        ssq[mi] += __shfl_xor(ssq[mi], 32, 64);
        ssk[mi] += __shfl_xor(ssk[mi], 16, 64);
        ssk[mi] += __shfl_xor(ssk[mi], 32, 64);
    }
    if (lane < 16) {
        float* sqb = sqp + batch * sqpstr + (long)cw * 384;
        #pragma unroll
        for (int mi = 0; mi < 3; mi++) {
            sqb[h * 48 + mi * 16 + lane] = ssq[mi];
            sqb[192 + h * 48 + mi * 16 + lane] = ssk[mi];
        }
    }
}

// ---------------- K3A2: coalesced two-stage reduce over cw (256 slots, 8 segs of 32)
__global__ __launch_bounds__(256) void k3a_reduce2(const float* __restrict__ Spt,
                                                   const float* __restrict__ sqp,
                                                   float* __restrict__ S1,
                                                   float* __restrict__ sq1,
                                                   long Sptstr, long sqpstr, long S1str, long sq1str) {
    const int seg = blockIdx.y;
    const int batch = blockIdx.z;
    const int w = blockIdx.x * 256 + threadIdx.x;
    if (w < 9216) {
        const float* p = Spt + batch * Sptstr + (long)seg * 32 * 9216 + w;
        float s = 0.f;
        for (int i = 0; i < 32; i++) s += p[(long)i * 9216];
        S1[batch * S1str + seg * 9216 + w] = s;
    } else if (w < 9600) {
        const int c = w - 9216;
        const float* p = sqp + batch * sqpstr + (long)seg * 32 * 384 + c;
        float s = 0.f;
        for (int i = 0; i < 32; i++) s += p[i * 384];
        sq1[batch * sq1str + seg * 384 + c] = s;
    }
}

// ---------------- K3B: norms, noise MLP, softmax, AND weff slice (k4 folded in)
__global__ __launch_bounds__(256) void k3b_attn_weff(const float* __restrict__ S1,
                                                     const float* __restrict__ sq1,
                                                     const float* __restrict__ noise,
                                                     const float* __restrict__ btemp,
                                                     const float* __restrict__ w_nm1,
                                                     const float* __restrict__ w_nm2,
                                                     const float* __restrict__ w_out,
                                                     ushort_t* __restrict__ weffb,
                                                     int b0, long S1str, long sq1str, long wstr) {
    __shared__ float sA[48][49];
    __shared__ float invq[48], invk[48];
    __shared__ float stemp;
    const int h = blockIdx.x, batch = blockIdx.y, tid = threadIdx.x;
    const float* S1b = S1 + batch * S1str;
    const float* sq1b = sq1 + batch * sq1str;
    for (int e = tid; e < 2304; e += 256) {
        float s = 0.f;
        #pragma unroll
        for (int seg = 0; seg < 8; seg++) s += S1b[seg * 9216 + h * 2304 + e];
        sA[e / 48][e % 48] = s;
    }
    if (tid < 96) {
        int c = (tid < 48) ? (h * 48 + tid) : (192 + h * 48 + (tid - 48));
        float s = 0.f;
        #pragma unroll
        for (int seg = 0; seg < 8; seg++) s += sq1b[seg * 384 + c];
        float inv = 1.f / fmaxf(sqrtf(s), 1e-12f);
        if (tid < 48) invq[tid] = inv; else invk[tid - 48] = inv;
    }
    if (tid == 0) {
        float nz = noise[b0 + batch];
        float a = 0.f;
        for (int i = 0; i < 48; i++) {
            float t = w_nm1[i] * nz;
            t = (t >= 0.f) ? t : 0.2f * t;
            a += w_nm2[h * 48 + i] * t;
        }
        float sig = 1.f / (1.f + expf(-a));
        stemp = btemp[h] * (2.f - sig);
    }
    __syncthreads();
    for (int e = tid; e < 2304; e += 256) {
        int c = e / 48, d = e % 48;
        sA[c][d] *= invq[c] * invk[d] * stemp;
    }
    __syncthreads();
    if (tid < 48) {
        float m = -1e30f;
        for (int d = 0; d < 48; d++) m = fmaxf(m, sA[tid][d]);
        float sum = 0.f;
        for (int d = 0; d < 48; d++) {
            float e_ = expf(sA[tid][d] - m);
            sA[tid][d] = e_;
            sum += e_;
        }
        float r = 1.f / sum;
        for (int d = 0; d < 48; d++) sA[tid][d] *= r;
    }
    __syncthreads();
    ushort_t* wb = weffb + batch * wstr;
    for (int e = tid; e < 9216; e += 256) {
        int o = e / 48, d = e % 48;
        const float* wr = w_out + o * 192 + h * 48;
        float s = 0.f;
        #pragma unroll
        for (int c = 0; c < 48; c++) s += wr[c] * sA[c][d];
        wb[o * 192 + h * 48 + d] = f2b(s);
    }
}

extern "C" void kernel_launch(void* const* d_in, const int* in_sizes, int n_in,
                              void* d_out, int out_size, void* d_ws, size_t ws_size,
                              hipStream_t stream) {
    const float* x      = (const float*)d_in[0];
    const float* noise  = (const float*)d_in[1];
    const float* btemp  = (const float*)d_in[2];
    const float* w_nm1  = (const float*)d_in[3];
    const float* w_nm2  = (const float*)d_in[4];
    const float* w_qkv  = (const float*)d_in[5];
    const float* w_dw   = (const float*)d_in[6];
    const float* w_out  = (const float*)d_in[7];
    float* out = (float*)d_out;
    float* ws = (float*)d_ws;

    const long need2 = 80603136L;  // floats for disjoint 2-batch layout (322.4 MB)
    if ((long)(ws_size / 4) >= need2) {
        // ---- combined 2-batch path: 6 dispatches total, no aliasing
        ushort_t* qkvb = (ushort_t*)ws;                       // 2 x 576*NPIX bf16
        ushort_t* dwv  = (ushort_t*)(ws + 37748736);          // 2 x 192*NPIX bf16
        ushort_t* dwb  = (ushort_t*)(ws + 50331648);          // 2 x 384*NPIX bf16
        float* Spt  = ws + 75497472;                          // 2 x 2359296
        float* sqp  = ws + 80216064;                          // 2 x 98304
        float* S1   = ws + 80412672;                          // 2 x 73728
        float* sq1  = ws + 80560128;                          // 2 x 3072
        ushort_t* weffb = (ushort_t*)(ws + 80566272);         // 2 x 36864 bf16

        kgemm_fused<1, 0, 1><<<dim3(1024, 2), 256, 0, stream>>>(
            w_qkv, x, qkvb, 9, 0L, 192L * NPIX, 576L * NPIX);
        kdw_conv<<<dim3(16, 576, 2), 256, 0, stream>>>(
            qkvb, w_dw, dwb, dwv, 576L * NPIX, 384L * NPIX, 192L * NPIX);
        k2_gram_mfma<<<dim3(64, 4, 2), 256, 0, stream>>>(
            dwb, Spt, sqp, 384L * NPIX, 2359296L, 98304L);
        k3a_reduce2<<<dim3(38, 8, 2), 256, 0, stream>>>(
            Spt, sqp, S1, sq1, 2359296L, 98304L, 73728L, 3072L);
        k3b_attn_weff<<<dim3(4, 2), 256, 0, stream>>>(
            S1, sq1, noise, btemp, w_nm1, w_nm2, w_out, weffb, 0, 73728L, 3072L, 36864L);
        kgemm_fused<0, 1, 0><<<dim3(1024, 2), 256, 0, stream>>>(
            weffb, dwv, out, 3, 36864L, 192L * NPIX, 192L * NPIX);
    } else {
        // ---- fallback: proven single-batch aliased layout (152 MB), sequential
        ushort_t* qkvb = (ushort_t*)ws;
        float* Spt  = ws;                      // 2,359,296
        float* sqp  = ws + 9437184;            // 98,304
        float* S1   = ws + 9830400;            // 73,728
        float* sq1  = ws + 9904128;            // 3,072
        ushort_t* weffb = (ushort_t*)(ws + 9907200);
        ushort_t* dwv = (ushort_t*)(ws + 18874368);
        ushort_t* dwb = (ushort_t*)(ws + 25427968);

        for (int b = 0; b < 2; b++) {
            const float* xb = x + (long)b * 192 * NPIX;
            float* outb = out + (long)b * 192 * NPIX;
            kgemm_fused<1, 0, 1><<<dim3(1024, 1), 256, 0, stream>>>(
                w_qkv, xb, qkvb, 9, 0L, 0L, 0L);
            kdw_conv<<<dim3(16, 576, 1), 256, 0, stream>>>(
                qkvb, w_dw, dwb, dwv, 0L, 0L, 0L);
            k2_gram_mfma<<<dim3(64, 4, 1), 256, 0, stream>>>(
                dwb, Spt, sqp, 0L, 0L, 0L);
            k3a_reduce2<<<dim3(38, 8, 1), 256, 0, stream>>>(
                Spt, sqp, S1, sq1, 0L, 0L, 0L, 0L);
            k3b_attn_weff<<<dim3(4, 1), 256, 0, stream>>>(
                S1, sq1, noise, btemp, w_nm1, w_nm2, w_out, weffb, b, 0L, 0L, 0L);
            kgemm_fused<0, 1, 0><<<dim3(1024, 1), 256, 0, stream>>>(
                weffb, dwv, outb, 3, 0L, 0L, 0L);
        }
    }
}

// Round 14
// 237.413 us; speedup vs baseline: 1.2267x; 1.2267x over previous
//
#include <hip/hip_runtime.h>
#include <hip/hip_bf16.h>

#define NPIX 65536
#define IW 256

typedef unsigned short ushort_t;
typedef __attribute__((ext_vector_type(8))) short bf16x8;
typedef __attribute__((ext_vector_type(4))) float f32x4;

__device__ __forceinline__ float b2f(ushort_t u) {
    union { unsigned int i; float f; } v;
    v.i = ((unsigned int)u) << 16;
    return v.f;
}
__device__ __forceinline__ ushort_t f2b(float f) {
    __hip_bfloat16 h = __float2bfloat16(f);
    return *reinterpret_cast<ushort_t*>(&h);
}

// ---------------- KGEMM (B-stationary, fused transpose staging, MFMA bf16)
// C[m][n] = sum_k A[m][k] * B[k][n];  B source is row-major [192][NPIX]
// (fp32 if B_F32 else bf16). grid = 512 n-tiles of 128.
// Best measured config (r11): 128n tile, 76.8KB LDS, 2 blocks/CU.
template<int B_F32, int A_BF16, int OUT_BF16>
__global__ __launch_bounds__(256) void kgemm_fused(const void* __restrict__ Aptr,
                                                   const void* __restrict__ Bsrc,
                                                   void* __restrict__ Cout,
                                                   int mtiles) {
    __shared__ ushort_t Bs[128 * 200];
    __shared__ ushort_t AsLu[64 * 200];   // Lu[192][66] during B-stage; As after
    const int tid = threadIdx.x;
    const int lane = tid & 63;
    const int wave = tid >> 6;
    const long n_base = (long)blockIdx.x * 128;

    // ---- B-stage with in-LDS transpose: two 64-px halves
    ushort_t (*Lu)[66] = reinterpret_cast<ushort_t (*)[66]>(AsLu);
    #pragma unroll
    for (int half = 0; half < 2; half++) {
        const long n0 = n_base + half * 64;
        __syncthreads();  // Lu reuse between halves
        #pragma unroll
        for (int i = 0; i < 24; i++) {     // 192 rows x 32 elem-pairs
            int e = tid + i * 256;
            int k = e >> 5, n2 = e & 31;
            ushort2 o;
            if (B_F32) {
                float2 v = *reinterpret_cast<const float2*>(
                    (const float*)Bsrc + (long)k * NPIX + n0 + n2 * 2);
                o = make_ushort2(f2b(v.x), f2b(v.y));
            } else {
                o = *reinterpret_cast<const ushort2*>(
                    (const ushort_t*)Bsrc + (long)k * NPIX + n0 + n2 * 2);
            }
            *reinterpret_cast<ushort2*>(&Lu[k][n2 * 2]) = o;
        }
        __syncthreads();
        const int n = tid >> 2, seg = tid & 3;
        const int kb = seg * 48;
        ushort_t* dst = &Bs[(half * 64 + n) * 200 + kb];
        #pragma unroll
        for (int w = 0; w < 6; w++) {
            unsigned int p0 = (unsigned int)Lu[kb + w * 8 + 0][n] | ((unsigned int)Lu[kb + w * 8 + 1][n] << 16);
            unsigned int p1 = (unsigned int)Lu[kb + w * 8 + 2][n] | ((unsigned int)Lu[kb + w * 8 + 3][n] << 16);
            unsigned int p2 = (unsigned int)Lu[kb + w * 8 + 4][n] | ((unsigned int)Lu[kb + w * 8 + 5][n] << 16);
            unsigned int p3 = (unsigned int)Lu[kb + w * 8 + 6][n] | ((unsigned int)Lu[kb + w * 8 + 7][n] << 16);
            *reinterpret_cast<int4*>(dst + w * 8) = make_int4(p0, p1, p2, p3);
        }
    }

    const int r15 = lane & 15;
    const int g8 = (lane >> 4) * 8;
    const int gq = (lane >> 4) * 4;
    const int nw = wave * 32;

    // ---- m-tile loop; AsLu now holds the A tile
    for (int mt = 0; mt < mtiles; mt++) {
        const int m_base = mt * 64;
        __syncthreads();
        #pragma unroll
        for (int i = 0; i < 12; i++) {     // 64 x 48 ushort4 chunks
            int c = tid + i * 256;
            int m = c / 48, k4 = c % 48;
            if (A_BF16) {
                const ushort_t* A = (const ushort_t*)Aptr;
                ushort4 v = *reinterpret_cast<const ushort4*>(A + (long)(m_base + m) * 192 + k4 * 4);
                *reinterpret_cast<ushort4*>(&AsLu[m * 200 + k4 * 4]) = v;
            } else {
                const float* A = (const float*)Aptr;
                float4 v = *reinterpret_cast<const float4*>(A + (long)(m_base + m) * 192 + k4 * 4);
                ushort4 o = make_ushort4(f2b(v.x), f2b(v.y), f2b(v.z), f2b(v.w));
                *reinterpret_cast<ushort4*>(&AsLu[m * 200 + k4 * 4]) = o;
            }
        }
        __syncthreads();

        f32x4 acc[4][2];
        #pragma unroll
        for (int mi = 0; mi < 4; mi++)
            #pragma unroll
            for (int ni = 0; ni < 2; ni++)
                acc[mi][ni] = (f32x4){0.f, 0.f, 0.f, 0.f};

        #pragma unroll
        for (int kk = 0; kk < 192; kk += 32) {
            bf16x8 a[4], b[2];
            #pragma unroll
            for (int mi = 0; mi < 4; mi++)
                a[mi] = *reinterpret_cast<const bf16x8*>(&AsLu[(mi * 16 + r15) * 200 + kk + g8]);
            #pragma unroll
            for (int ni = 0; ni < 2; ni++)
                b[ni] = *reinterpret_cast<const bf16x8*>(&Bs[(nw + ni * 16 + r15) * 200 + kk + g8]);
            #pragma unroll
            for (int mi = 0; mi < 4; mi++)
                #pragma unroll
                for (int ni = 0; ni < 2; ni++)
                    acc[mi][ni] = __builtin_amdgcn_mfma_f32_16x16x32_bf16(a[mi], b[ni], acc[mi][ni], 0, 0, 0);
        }

        #pragma unroll
        for (int mi = 0; mi < 4; mi++)
            #pragma unroll
            for (int ni = 0; ni < 2; ni++)
                #pragma unroll
                for (int r = 0; r < 4; r++) {
                    long m = m_base + mi * 16 + gq + r;
                    long n = n_base + nw + ni * 16 + r15;
                    if (OUT_BF16) ((ushort_t*)Cout)[m * NPIX + n] = f2b(acc[mi][ni][r]);
                    else          ((float*)Cout)[m * NPIX + n] = acc[mi][ni][r];
                }
    }
}

// ---------------- KDW: register-sliding-window depthwise 3x3, 16 rows/block.
// grid (16, 576); thread (ty,tx16) computes 16 contiguous px of one row.
__global__ __launch_bounds__(256) void kdw_conv(const ushort_t* __restrict__ qkvb,
                                                const float* __restrict__ wdw,
                                                ushort_t* __restrict__ dwb,
                                                ushort_t* __restrict__ dwv) {
    __shared__ ushort_t rows[18][IW];
    const int tid = threadIdx.x;
    const int j = blockIdx.y;
    const int y0 = blockIdx.x * 16;
    const ushort_t* src = qkvb + (long)j * NPIX;
    ushort_t* dst = (j < 384) ? (dwb + (long)j * NPIX) : (dwv + (long)(j - 384) * NPIX);
    float wv[9];
    #pragma unroll
    for (int t = 0; t < 9; t++) wv[t] = wdw[j * 9 + t];

    // stage 18 rows (halo y0-1 .. y0+16) as ushort4
    for (int e = tid; e < 18 * 64; e += 256) {
        int r = e >> 6, x4 = e & 63;
        int yy = y0 - 1 + r;
        ushort4 val = (yy >= 0 && yy <= 255)
            ? *reinterpret_cast<const ushort4*>(src + yy * IW + x4 * 4)
            : make_ushort4(0, 0, 0, 0);
        *reinterpret_cast<ushort4*>(&rows[r][x4 * 4]) = val;
    }
    __syncthreads();

    const int ty = tid >> 4;
    const int tx = (tid & 15) * 16;
    float win[3][18];
    #pragma unroll
    for (int dy = 0; dy < 3; dy++) {
        const ushort_t* rw = rows[ty + dy];
        win[dy][0] = (tx > 0) ? b2f(rw[tx - 1]) : 0.f;
        #pragma unroll
        for (int i = 0; i < 16; i++) win[dy][i + 1] = b2f(rw[tx + i]);
        win[dy][17] = (tx < 240) ? b2f(rw[tx + 16]) : 0.f;
    }

    unsigned int packed[8];
    #pragma unroll
    for (int p2 = 0; p2 < 8; p2++) {
        unsigned int pk = 0;
        #pragma unroll
        for (int half = 0; half < 2; half++) {
            const int p = p2 * 2 + half;
            float a = 0.f;
            #pragma unroll
            for (int dy = 0; dy < 3; dy++)
                #pragma unroll
                for (int dx = 0; dx < 3; dx++)
                    a += wv[dy * 3 + dx] * win[dy][p + dx];
            pk |= ((unsigned int)f2b(a)) << (16 * half);
        }
        packed[p2] = pk;
    }
    int4* dp = reinterpret_cast<int4*>(dst + (y0 + ty) * IW + tx);
    dp[0] = make_int4(packed[0], packed[1], packed[2], packed[3]);
    dp[1] = make_int4(packed[4], packed[5], packed[6], packed[7]);
}

// ---------------- K2G: MFMA Gram partials, fragments straight from global.
// grid (64 chunks, 4 heads), 4 waves; wave owns 256-px K-slice (8 MFMA K-steps).
__global__ __launch_bounds__(256) void k2_gram_mfma(const ushort_t* __restrict__ dwb,
                                                    float* __restrict__ Spt,
                                                    float* __restrict__ sqp) {
    const int tid = threadIdx.x;
    const int lane = tid & 63;
    const int wave = tid >> 6;
    const int chunk = blockIdx.x;
    const int h = blockIdx.y;
    const int r15 = lane & 15;
    const int g = lane >> 4;
    const long n0 = (long)chunk * 1024 + wave * 256;
    const ushort_t* qb = dwb + (long)(h * 48) * NPIX + n0;
    const ushort_t* kb = dwb + (long)(192 + h * 48) * NPIX + n0;

    f32x4 acc[3][3];
    #pragma unroll
    for (int mi = 0; mi < 3; mi++)
        #pragma unroll
        for (int nj = 0; nj < 3; nj++)
            acc[mi][nj] = (f32x4){0.f, 0.f, 0.f, 0.f};
    float ssq[3] = {0.f, 0.f, 0.f}, ssk[3] = {0.f, 0.f, 0.f};

    for (int ks = 0; ks < 8; ks++) {
        const int off = ks * 32 + g * 8;
        bf16x8 a[3], bfr[3];
        #pragma unroll
        for (int mi = 0; mi < 3; mi++)
            a[mi] = *reinterpret_cast<const bf16x8*>(qb + (long)(mi * 16 + r15) * NPIX + off);
        #pragma unroll
        for (int nj = 0; nj < 3; nj++)
            bfr[nj] = *reinterpret_cast<const bf16x8*>(kb + (long)(nj * 16 + r15) * NPIX + off);
        #pragma unroll
        for (int mi = 0; mi < 3; mi++)
            #pragma unroll
            for (int j = 0; j < 8; j++) {
                float f = b2f((ushort_t)a[mi][j]);
                ssq[mi] += f * f;
            }
        #pragma unroll
        for (int nj = 0; nj < 3; nj++)
            #pragma unroll
            for (int j = 0; j < 8; j++) {
                float f = b2f((ushort_t)bfr[nj][j]);
                ssk[nj] += f * f;
            }
        #pragma unroll
        for (int mi = 0; mi < 3; mi++)
            #pragma unroll
            for (int nj = 0; nj < 3; nj++)
                acc[mi][nj] = __builtin_amdgcn_mfma_f32_16x16x32_bf16(a[mi], bfr[nj], acc[mi][nj], 0, 0, 0);
    }

    const int cw = chunk * 4 + wave;
    float* outb = Spt + (long)cw * 9216 + h * 2304;
    const int gq = g * 4;
    #pragma unroll
    for (int mi = 0; mi < 3; mi++)
        #pragma unroll
        for (int nj = 0; nj < 3; nj++)
            #pragma unroll
            for (int r = 0; r < 4; r++)
                outb[(mi * 16 + gq + r) * 48 + nj * 16 + r15] = acc[mi][nj][r];

    #pragma unroll
    for (int mi = 0; mi < 3; mi++) {
        ssq[mi] += __shfl_xor(ssq[mi], 16, 64);
        ssq[mi] += __shfl_xor(ssq[mi], 32, 64);
        ssk[mi] += __shfl_xor(ssk[mi], 16, 64);
        ssk[mi] += __shfl_xor(ssk[mi], 32, 64);
    }
    if (lane < 16) {
        float* sqb = sqp + (long)cw * 384;
        #pragma unroll
        for (int mi = 0; mi < 3; mi++) {
            sqb[h * 48 + mi * 16 + lane] = ssq[mi];
            sqb[192 + h * 48 + mi * 16 + lane] = ssk[mi];
        }
    }
}

// ---------------- K3A2: coalesced two-stage reduce over cw (256 slots, 8 segs of 32)
__global__ __launch_bounds__(256) void k3a_reduce2(const float* __restrict__ Spt,
                                                   const float* __restrict__ sqp,
                                                   float* __restrict__ S1,
                                                   float* __restrict__ sq1) {
    const int seg = blockIdx.y;
    const int w = blockIdx.x * 256 + threadIdx.x;
    if (w < 9216) {
        const float* p = Spt + (long)seg * 32 * 9216 + w;
        float s = 0.f;
        for (int i = 0; i < 32; i++) s += p[(long)i * 9216];
        S1[seg * 9216 + w] = s;
    } else if (w < 9600) {
        const int c = w - 9216;
        const float* p = sqp + (long)seg * 32 * 384 + c;
        float s = 0.f;
        for (int i = 0; i < 32; i++) s += p[i * 384];
        sq1[seg * 384 + c] = s;
    }
}

// ---------------- K3b: norms, noise MLP, softmax -> attn[4][48][48]
__global__ __launch_bounds__(256) void k3b_attn(const float* __restrict__ S1,
                                                const float* __restrict__ sq1,
                                                const float* __restrict__ noise,
                                                const float* __restrict__ btemp,
                                                const float* __restrict__ w_nm1,
                                                const float* __restrict__ w_nm2,
                                                float* __restrict__ attn, int b) {
    __shared__ float sA[48][49];
    __shared__ float invq[48], invk[48];
    __shared__ float stemp;
    const int h = blockIdx.x, tid = threadIdx.x;
    for (int e = tid; e < 2304; e += 256) {
        float s = 0.f;
        #pragma unroll
        for (int seg = 0; seg < 8; seg++) s += S1[seg * 9216 + h * 2304 + e];
        sA[e / 48][e % 48] = s;
    }
    if (tid < 96) {
        int c = (tid < 48) ? (h * 48 + tid) : (192 + h * 48 + (tid - 48));
        float s = 0.f;
        #pragma unroll
        for (int seg = 0; seg < 8; seg++) s += sq1[seg * 384 + c];
        float inv = 1.f / fmaxf(sqrtf(s), 1e-12f);
        if (tid < 48) invq[tid] = inv; else invk[tid - 48] = inv;
    }
    if (tid == 0) {
        float nz = noise[b];
        float a = 0.f;
        for (int i = 0; i < 48; i++) {
            float t = w_nm1[i] * nz;
            t = (t >= 0.f) ? t : 0.2f * t;
            a += w_nm2[h * 48 + i] * t;
        }
        float sig = 1.f / (1.f + expf(-a));
        stemp = btemp[h] * (2.f - sig);
    }
    __syncthreads();
    for (int e = tid; e < 2304; e += 256) {
        int c = e / 48, d = e % 48;
        sA[c][d] *= invq[c] * invk[d] * stemp;
    }
    __syncthreads();
    if (tid < 48) {
        float m = -1e30f;
        for (int d = 0; d < 48; d++) m = fmaxf(m, sA[tid][d]);
        float sum = 0.f;
        for (int d = 0; d < 48; d++) {
            float e_ = expf(sA[tid][d] - m);
            sA[tid][d] = e_;
            sum += e_;
        }
        float r = 1.f / sum;
        for (int d = 0; d < 48; d++)
            attn[h * 2304 + tid * 48 + d] = sA[tid][d] * r;
    }
}

// ---------------- K4: W_eff[o][j] bf16 = sum_c w_out[o][h*48+c] * attn[h][c][d]
__global__ __launch_bounds__(256) void k4_weff(const float* __restrict__ w_out,
                                               const float* __restrict__ attn,
                                               ushort_t* __restrict__ weffb) {
    int e = blockIdx.x * 256 + threadIdx.x;
    int o = e / 192, j = e % 192;
    int h = j / 48, d = j % 48;
    const float* wr = w_out + o * 192 + h * 48;
    const float* ar = attn + h * 2304 + d;
    float s = 0.f;
    #pragma unroll
    for (int c = 0; c < 48; c++) s += wr[c] * ar[c * 48];
    weffb[e] = f2b(s);
}

extern "C" void kernel_launch(void* const* d_in, const int* in_sizes, int n_in,
                              void* d_out, int out_size, void* d_ws, size_t ws_size,
                              hipStream_t stream) {
    const float* x      = (const float*)d_in[0];
    const float* noise  = (const float*)d_in[1];
    const float* btemp  = (const float*)d_in[2];
    const float* w_nm1  = (const float*)d_in[3];
    const float* w_nm2  = (const float*)d_in[4];
    const float* w_qkv  = (const float*)d_in[5];
    const float* w_dw   = (const float*)d_in[6];
    const float* w_out  = (const float*)d_in[7];
    float* out = (float*)d_out;
    float* ws = (float*)d_ws;

    // Workspace (float-slot offsets), peak 38,010,880 floats = 152.0 MB:
    //  region A [0, 18874368): qkvb bf16[576][NPIX] (live kgemm1..kdw)
    //    - after kdw: Spt[256][9216], sqp[256][384], S1, sq1, attn, weffb alias it
    //  region B [18874368, 25165824): dwv bf16[192][NPIX] (kdw..kgemm2)
    //  region C [25427968, 38010880): dwb bf16[384][NPIX] (kdw..k2g)
    ushort_t* qkvb = (ushort_t*)ws;
    float* Spt  = ws;                      // 2,359,296
    float* sqp  = ws + 9437184;            // 98,304
    float* S1   = ws + 9830400;            // 73,728
    float* sq1  = ws + 9904128;            // 3,072
    float* attn = ws + 9907200;            // 9,216
    ushort_t* weffb = (ushort_t*)(ws + 9916416);
    ushort_t* dwv = (ushort_t*)(ws + 18874368);
    ushort_t* dwb = (ushort_t*)(ws + 25427968);

    for (int b = 0; b < 2; b++) {
        const float* xb = x + (long)b * 192 * NPIX;
        float* outb = out + (long)b * 192 * NPIX;
        kgemm_fused<1, 0, 1><<<512, 256, 0, stream>>>(w_qkv, xb, qkvb, 9);
        kdw_conv<<<dim3(16, 576), 256, 0, stream>>>(qkvb, w_dw, dwb, dwv);
        k2_gram_mfma<<<dim3(64, 4), 256, 0, stream>>>(dwb, Spt, sqp);
        k3a_reduce2<<<dim3(38, 8), 256, 0, stream>>>(Spt, sqp, S1, sq1);
        k3b_attn<<<4, 256, 0, stream>>>(S1, sq1, noise, btemp, w_nm1, w_nm2, attn, b);
        k4_weff<<<144, 256, 0, stream>>>(w_out, attn, weffb);
        kgemm_fused<0, 1, 0><<<512, 256, 0, stream>>>(weffb, dwv, outb, 3);
    }
}